// Round 4
// baseline (1597.817 us; speedup 1.0000x reference)
//
#include <hip/hip_runtime.h>

#define BB 4
#define SS 1024
#define HH 2048
#define NQH 32
#define NKVH 4
#define DD 128
#define EQKV 5120   // (NQH + 2*NKVH) * DD

typedef __attribute__((ext_vector_type(8))) short s8v;
typedef __attribute__((ext_vector_type(4))) float f4v;

__device__ __forceinline__ unsigned short f2bf(float f) {
  unsigned int u = __builtin_bit_cast(unsigned int, f);
  u += 0x7fffu + ((u >> 16) & 1u);
  return (unsigned short)(u >> 16);
}
__device__ __forceinline__ float bf2f(unsigned short s) {
  unsigned int u = ((unsigned int)s) << 16;
  return __builtin_bit_cast(float, u);
}

// C[M,N] = A[M,K] (row stride lda) @ B[K,N], fp32 accumulate, bf16 MFMA.
// AF32/BF32: operand stored as fp32 (converted to bf16 during LDS staging).
// CF32: write C as fp32 (else bf16).
// 64x64 tile per 256-thread block; 4 waves 2x2; each wave 32x32 via 2x2 MFMA tiles.
template <bool AF32, bool BF32, bool CF32>
__global__ __launch_bounds__(256) void gemm_t(const void* __restrict__ Ap,
                                              const void* __restrict__ Bp,
                                              void* __restrict__ Cp,
                                              int M, int N, int K, int lda) {
  __shared__ unsigned short As[64][40];   // [m][k], pad to 40 shorts (80B rows, 16B-aligned)
  __shared__ unsigned short Bs[64][40];   // transposed: [n][k]
  const int tid  = threadIdx.x;
  const int lane = tid & 63;
  const int wave = tid >> 6;
  const int la   = lane & 15;
  const int quad = lane >> 4;
  const int m0 = blockIdx.y * 64;
  const int n0 = blockIdx.x * 64;
  const int wm = (wave >> 1) * 32;
  const int wn = (wave & 1) * 32;
  f4v acc[2][2] = {};

  const int ar = tid >> 2, ac = (tid & 3) * 8;   // A: 64 rows x (4 thr * 8 elem)
  const int bk = tid >> 3, bn = (tid & 7) * 8;   // B: 32 rows x (8 thr * 8 elem)

  for (int k0 = 0; k0 < K; k0 += 32) {
    // ---- load A row fragment (8 elems) ----
    s8v av;
    if constexpr (AF32) {
      const float* a = (const float*)Ap + (size_t)(m0 + ar) * lda + ac + k0;
      f4v v0 = *reinterpret_cast<const f4v*>(a);
      f4v v1 = *reinterpret_cast<const f4v*>(a + 4);
#pragma unroll
      for (int j = 0; j < 4; ++j) { av[j] = (short)f2bf(v0[j]); av[j + 4] = (short)f2bf(v1[j]); }
    } else {
      av = *reinterpret_cast<const s8v*>((const unsigned short*)Ap + (size_t)(m0 + ar) * lda + ac + k0);
    }
    // ---- load B row fragment (8 elems) ----
    unsigned short bvs[8];
    if constexpr (BF32) {
      const float* bp = (const float*)Bp + (size_t)(k0 + bk) * N + n0 + bn;
      f4v v0 = *reinterpret_cast<const f4v*>(bp);
      f4v v1 = *reinterpret_cast<const f4v*>(bp + 4);
#pragma unroll
      for (int j = 0; j < 4; ++j) { bvs[j] = f2bf(v0[j]); bvs[j + 4] = f2bf(v1[j]); }
    } else {
      s8v bv = *reinterpret_cast<const s8v*>((const unsigned short*)Bp + (size_t)(k0 + bk) * N + n0 + bn);
#pragma unroll
      for (int j = 0; j < 8; ++j) bvs[j] = (unsigned short)bv[j];
    }
    *reinterpret_cast<s8v*>(&As[ar][ac]) = av;
#pragma unroll
    for (int j = 0; j < 8; ++j) Bs[bn + j][bk] = bvs[j];
    __syncthreads();
#pragma unroll
    for (int mi = 0; mi < 2; ++mi) {
      s8v af = *reinterpret_cast<const s8v*>(&As[wm + mi * 16 + la][quad * 8]);
#pragma unroll
      for (int ni = 0; ni < 2; ++ni) {
        s8v bf = *reinterpret_cast<const s8v*>(&Bs[wn + ni * 16 + la][quad * 8]);
        acc[mi][ni] = __builtin_amdgcn_mfma_f32_16x16x32_bf16(af, bf, acc[mi][ni], 0, 0, 0);
      }
    }
    __syncthreads();
  }
#pragma unroll
  for (int mi = 0; mi < 2; ++mi)
#pragma unroll
    for (int ni = 0; ni < 2; ++ni)
#pragma unroll
      for (int r = 0; r < 4; ++r) {
        int row = m0 + wm + mi * 16 + quad * 4 + r;
        int col = n0 + wn + ni * 16 + la;
        if constexpr (CF32) ((float*)Cp)[(size_t)row * N + col] = acc[mi][ni][r];
        else ((unsigned short*)Cp)[(size_t)row * N + col] = f2bf(acc[mi][ni][r]);
      }
}

// In-place RMSNorm + RoPE on the Q/K slices of one batch's qkv [SS, EQKV] (bf16).
// One wave per (s, head). Head h occupies cols [h*DD,(h+1)*DD), h in 0..35.
// qw/kw/cos/sin are fp32. cos/sin indexed by s only (b-invariant).
__global__ __launch_bounds__(64) void norm_rope(unsigned short* __restrict__ qkv,
                                                const float* __restrict__ qw,
                                                const float* __restrict__ kw,
                                                const float* __restrict__ cosp,
                                                const float* __restrict__ sinp) {
  const int h = blockIdx.x;    // 0..35: 0..31 Q, 32..35 K
  const int s = blockIdx.y;    // 0..1023
  const int lane = threadIdx.x;
  const int d0 = lane * 2;
  unsigned short* p = qkv + (size_t)s * EQKV + h * DD + d0;
  unsigned int u = *reinterpret_cast<const unsigned int*>(p);
  float x0 = bf2f((unsigned short)(u & 0xffff));
  float x1 = bf2f((unsigned short)(u >> 16));
  float ss = x0 * x0 + x1 * x1;
#pragma unroll
  for (int off = 32; off >= 1; off >>= 1) ss += __shfl_xor(ss, off);
  float rs = rsqrtf(ss * (1.0f / 128.0f) + 1e-6f);
  const float* w = (h < NQH) ? qw : kw;
  float n0 = x0 * rs * w[d0];
  float n1 = x1 * rs * w[d0 + 1];
  float o0 = __shfl_xor(n0, 32);
  float o1 = __shfl_xor(n1, 32);
  float r0 = (lane < 32) ? -o0 : o0;  // rotate_half
  float r1 = (lane < 32) ? -o1 : o1;
  float c0 = cosp[(size_t)s * DD + d0], c1 = cosp[(size_t)s * DD + d0 + 1];
  float s0 = sinp[(size_t)s * DD + d0], s1 = sinp[(size_t)s * DD + d0 + 1];
  float y0 = n0 * c0 + r0 * s0;
  float y1 = n1 * c1 + r1 * s1;
  unsigned int out = (unsigned int)f2bf(y0) | ((unsigned int)f2bf(y1) << 16);
  *reinterpret_cast<unsigned int*>(p) = out;
}

// Flash attention on one batch's qkv [SS, EQKV] (bf16); writes O over the Q slice.
// Safe in-place: block (tile,h) is the only reader AND writer of its Q slice,
// and its Q reads complete before any write (data dependence through the MFMAs).
__global__ __launch_bounds__(64) void attn(unsigned short* __restrict__ qkv) {
  const int tile = blockIdx.x;  // 0..63
  const int h = blockIdx.y;     // 0..31
  const int hkv = h >> 3;       // NQ/NKV = 8
  const int lane = threadIdx.x;
  const int la = lane & 15;
  const int quad = lane >> 4;
  const int qr0 = tile * 16;
  __shared__ unsigned short P[16][32];
  __shared__ unsigned short V[32][128];

  s8v qf[4];
  {
    const unsigned short* qrow = qkv + (size_t)(qr0 + la) * EQKV + h * DD;
#pragma unroll
    for (int t = 0; t < 4; ++t)
      qf[t] = *reinterpret_cast<const s8v*>(qrow + t * 32 + quad * 8);
  }
  const unsigned short* kbase = qkv + (NQH + hkv) * DD;
  const unsigned short* vbase = qkv + (NQH + NKVH + hkv) * DD;

  float m[4], l[4], al[4];
  f4v acc[8] = {};
#pragma unroll
  for (int r = 0; r < 4; ++r) { m[r] = -1.0e30f; l[r] = 0.f; }

  const float scale = 0.08838834764831845f;  // 1/sqrt(128)
  const int nkb = (qr0 + 16 + 31) >> 5;
  for (int kb = 0; kb < nkb; ++kb) {
    const int key0 = kb * 32;
    __syncthreads();  // prev-iter P/V reads complete before overwrite
    // stage V block [32][128]
#pragma unroll
    for (int i = 0; i < 8; ++i) {
      int c = i * 64 + lane;
      int row = c >> 4, col = (c & 15) * 8;
      *reinterpret_cast<s8v*>(&V[row][col]) =
          *reinterpret_cast<const s8v*>(vbase + (size_t)(key0 + row) * EQKV + col);
    }
    // scores: two 16-key MFMA column tiles
    f4v s0 = {}, s1 = {};
#pragma unroll
    for (int t = 0; t < 4; ++t) {
      s8v k0f = *reinterpret_cast<const s8v*>(kbase + (size_t)(key0 + la) * EQKV + t * 32 + quad * 8);
      s8v k1f = *reinterpret_cast<const s8v*>(kbase + (size_t)(key0 + 16 + la) * EQKV + t * 32 + quad * 8);
      s0 = __builtin_amdgcn_mfma_f32_16x16x32_bf16(qf[t], k0f, s0, 0, 0, 0);
      s1 = __builtin_amdgcn_mfma_f32_16x16x32_bf16(qf[t], k1f, s1, 0, 0, 0);
    }
    // online softmax; row = quad*4+r, its 32 keys spread over the quad's 16 lanes
#pragma unroll
    for (int r = 0; r < 4; ++r) {
      int q = qr0 + quad * 4 + r;
      float v0 = (key0 + la <= q) ? s0[r] * scale : -1.0e30f;
      float v1 = (key0 + 16 + la <= q) ? s1[r] * scale : -1.0e30f;
      float mx = fmaxf(v0, v1);
#pragma unroll
      for (int off = 8; off >= 1; off >>= 1) mx = fmaxf(mx, __shfl_xor(mx, off));
      float mnew = fmaxf(m[r], mx);
      float p0 = __expf(v0 - mnew);
      float p1 = __expf(v1 - mnew);
      al[r] = __expf(m[r] - mnew);
      m[r] = mnew;
      float rsum = p0 + p1;
#pragma unroll
      for (int off = 8; off >= 1; off >>= 1) rsum += __shfl_xor(rsum, off);
      l[r] = l[r] * al[r] + rsum;
      P[quad * 4 + r][la] = f2bf(p0);
      P[quad * 4 + r][la + 16] = f2bf(p1);
    }
    // rescale accumulator: row r lives in component r
#pragma unroll
    for (int nt = 0; nt < 8; ++nt)
#pragma unroll
      for (int r = 0; r < 4; ++r) acc[nt][r] *= al[r];
    __syncthreads();  // P + V visible
    // PV: P[16,32] @ V[32,128]
    s8v pf = *reinterpret_cast<const s8v*>(&P[la][quad * 8]);
#pragma unroll
    for (int nt = 0; nt < 8; ++nt) {
      s8v vf;
#pragma unroll
      for (int j = 0; j < 8; ++j)
        vf[j] = (short)V[quad * 8 + j][nt * 16 + la];
      acc[nt] = __builtin_amdgcn_mfma_f32_16x16x32_bf16(pf, vf, acc[nt], 0, 0, 0);
    }
  }
  // write O over the Q slice
#pragma unroll
  for (int nt = 0; nt < 8; ++nt)
#pragma unroll
    for (int r = 0; r < 4; ++r) {
      int q = qr0 + quad * 4 + r;
      qkv[(size_t)q * EQKV + h * DD + nt * 16 + la] = f2bf(acc[nt][r] / l[r]);
    }
}

extern "C" void kernel_launch(void* const* d_in, const int* in_sizes, int n_in,
                              void* d_out, int out_size, void* d_ws, size_t ws_size,
                              hipStream_t stream) {
  // ALL inputs are fp32 per the reference (jnp.float32 everywhere).
  const float* hidden = (const float*)d_in[0];   // [B,S,H]
  const float* w_qkv  = (const float*)d_in[1];   // [H, 5120]
  const float* w_o    = (const float*)d_in[2];   // [4096, H]
  const float* q_w    = (const float*)d_in[3];   // [128]
  const float* k_w    = (const float*)d_in[4];   // [128]
  const float* cosp   = (const float*)d_in[5];   // [B,S,D] (b-invariant)
  const float* sinp   = (const float*)d_in[6];
  float* out = (float*)d_out;                    // [B,S,H] fp32

  // Per-batch workspace: one [1024, 5120] bf16 slab = 10 MiB (total d_ws use).
  unsigned short* qkvb = (unsigned short*)d_ws;

  for (int b = 0; b < BB; ++b) {
    const float* hb = hidden + (size_t)b * SS * HH;
    float* ob = out + (size_t)b * SS * HH;
    // 1) QKV projection: [1024,2048]f32 @ [2048,5120]f32 -> qkvb bf16
    gemm_t<true, true, false><<<dim3(EQKV / 64, SS / 64), 256, 0, stream>>>(
        hb, w_qkv, qkvb, SS, EQKV, HH, HH);
    // 2) in-place RMSNorm + RoPE on Q,K slices
    norm_rope<<<dim3(NQH + NKVH, SS), 64, 0, stream>>>(qkvb, q_w, k_w, cosp, sinp);
    // 3) causal GQA attention; output overwrites Q slice (cols 0..4095)
    attn<<<dim3(SS / 16, NQH), 64, 0, stream>>>(qkvb);
    // 4) output projection: [1024,4096]bf16(lda=5120) @ [4096,2048]f32 -> out fp32
    gemm_t<false, true, true><<<dim3(HH / 64, SS / 64), 256, 0, stream>>>(
        qkvb, w_o, ob, SS, HH, NQH * DD, EQKV);
  }
}

// Round 5
// 758.918 us; speedup vs baseline: 2.1054x; 2.1054x over previous
//
#include <hip/hip_runtime.h>

#define BB 4
#define SS 1024
#define HH 2048
#define NQH 32
#define NKVH 4
#define DD 128
#define EQKV 5120   // (NQH + 2*NKVH) * DD

typedef __attribute__((ext_vector_type(8))) short s8v;
typedef __attribute__((ext_vector_type(4))) short s4v;
typedef __attribute__((ext_vector_type(4))) float f4v;

__device__ __forceinline__ unsigned short f2bf(float f) {
  unsigned int u = __builtin_bit_cast(unsigned int, f);
  u += 0x7fffu + ((u >> 16) & 1u);
  return (unsigned short)(u >> 16);
}
__device__ __forceinline__ float bf2f(unsigned short s) {
  unsigned int u = ((unsigned int)s) << 16;
  return __builtin_bit_cast(float, u);
}

// async global->LDS, 16B per lane. LDS dst = wave-uniform base + lane*16 (m104).
__device__ __forceinline__ void async16(unsigned short* lds, const unsigned short* g) {
  __builtin_amdgcn_global_load_lds(
      (const __attribute__((address_space(1))) unsigned int*)g,
      (__attribute__((address_space(3))) unsigned int*)lds, 16, 0, 0);
}

// ---------------- fast path kernels ----------------

// fp32 -> bf16 elementwise, 4 elems/thread. n divisible by 4.
__global__ __launch_bounds__(256) void cvt_bf16(const float* __restrict__ in,
                                                unsigned short* __restrict__ out, int n) {
  int i = (blockIdx.x * 256 + threadIdx.x) * 4;
  if (i >= n) return;
  f4v v = *reinterpret_cast<const f4v*>(in + i);
  s4v o;
#pragma unroll
  for (int j = 0; j < 4; ++j) o[j] = (short)f2bf(v[j]);
  *reinterpret_cast<s4v*>(out + i) = o;
}

// out[n][k] = bf16(in[k][n]); in fp32 [K][N]. 64x64 LDS tile.
__global__ __launch_bounds__(256) void transpose_cvt(const float* __restrict__ in,
                                                     unsigned short* __restrict__ out,
                                                     int K, int N) {
  __shared__ unsigned short T[64][65];
  const int k0 = blockIdx.y * 64, n0 = blockIdx.x * 64;
  const int t = threadIdx.x;
  const int r = t >> 4, c4 = (t & 15) * 4;
#pragma unroll
  for (int i = 0; i < 4; ++i) {
    f4v v = *reinterpret_cast<const f4v*>(&in[(size_t)(k0 + r + i * 16) * N + n0 + c4]);
#pragma unroll
    for (int j = 0; j < 4; ++j) T[r + i * 16][c4 + j] = f2bf(v[j]);
  }
  __syncthreads();
#pragma unroll
  for (int i = 0; i < 4; ++i) {
    int n = r + i * 16;
    s4v o;
#pragma unroll
    for (int j = 0; j < 4; ++j) o[j] = (short)T[c4 + j][n];
    *reinterpret_cast<s4v*>(&out[(size_t)(n0 + n) * K + k0 + c4]) = o;
  }
}

// m97-structure GEMM: C[M,N] = A[M,K](lda) @ Bt[N,K]^T, bf16 in, fp32 acc.
// 128x128 tile, BK=32, 4 waves 2x2 (each 64x64 = 4x4 MFMA tiles), global_load_lds w=16.
template <bool CF32>
__global__ __launch_bounds__(256) void gemm_bt(const unsigned short* __restrict__ A,
                                               const unsigned short* __restrict__ Bt,
                                               void* __restrict__ Cp,
                                               int M, int N, int K, int lda) {
  __shared__ unsigned short As[128 * 32];  // [m][k], rows 64B, NO pad (global_load_lds)
  __shared__ unsigned short Bs[128 * 32];  // [n][k]
  const int tid = threadIdx.x;
  const int ln = tid & 63, wv = tid >> 6;
  const int la = ln & 15, quad = ln >> 4;
  const int m0 = blockIdx.y * 128, n0 = blockIdx.x * 128;
  const int wm = (wv >> 1) * 64, wn = (wv & 1) * 64;
  f4v acc[4][4] = {};

  // staging: lane ln covers row wv*16 + ln/4 (+0 or +64), col (ln&3)*8
  const int srow = wv * 16 + (ln >> 2);
  const int scol = (ln & 3) * 8;
  const unsigned short* Ab = A + (size_t)(m0 + srow) * lda + scol;
  const unsigned short* Bb = Bt + (size_t)(n0 + srow) * K + scol;
  unsigned short* AsW = &As[wv * 16 * 32];  // wave-uniform LDS base
  unsigned short* BsW = &Bs[wv * 16 * 32];

  for (int k0 = 0; k0 < K; k0 += 32) {
    async16(AsW,           Ab + k0);
    async16(AsW + 64 * 32, Ab + (size_t)64 * lda + k0);
    async16(BsW,           Bb + k0);
    async16(BsW + 64 * 32, Bb + (size_t)64 * K + k0);
    __syncthreads();  // drains vmcnt before barrier (compiler-inserted)
    s8v af[4], bf[4];
#pragma unroll
    for (int mi = 0; mi < 4; ++mi)
      af[mi] = *reinterpret_cast<const s8v*>(&As[(wm + mi * 16 + la) * 32 + quad * 8]);
#pragma unroll
    for (int ni = 0; ni < 4; ++ni)
      bf[ni] = *reinterpret_cast<const s8v*>(&Bs[(wn + ni * 16 + la) * 32 + quad * 8]);
#pragma unroll
    for (int mi = 0; mi < 4; ++mi)
#pragma unroll
      for (int ni = 0; ni < 4; ++ni)
        acc[mi][ni] = __builtin_amdgcn_mfma_f32_16x16x32_bf16(af[mi], bf[ni], acc[mi][ni], 0, 0, 0);
    __syncthreads();
  }
#pragma unroll
  for (int mi = 0; mi < 4; ++mi)
#pragma unroll
    for (int ni = 0; ni < 4; ++ni)
#pragma unroll
      for (int r = 0; r < 4; ++r) {
        int row = m0 + wm + mi * 16 + quad * 4 + r;
        int col = n0 + wn + ni * 16 + la;
        if constexpr (CF32) ((float*)Cp)[(size_t)row * N + col] = acc[mi][ni][r];
        else ((unsigned short*)Cp)[(size_t)row * N + col] = f2bf(acc[mi][ni][r]);
      }
}

// ---------------- slow-path (fallback) GEMM: convert-on-stage ----------------
template <bool AF32, bool BF32, bool CF32>
__global__ __launch_bounds__(256) void gemm_t(const void* __restrict__ Ap,
                                              const void* __restrict__ Bp,
                                              void* __restrict__ Cp,
                                              int M, int N, int K, int lda) {
  __shared__ unsigned short As[64][40];
  __shared__ unsigned short Bs[64][40];
  const int tid  = threadIdx.x;
  const int lane = tid & 63;
  const int wave = tid >> 6;
  const int la   = lane & 15;
  const int quad = lane >> 4;
  const int m0 = blockIdx.y * 64;
  const int n0 = blockIdx.x * 64;
  const int wm = (wave >> 1) * 32;
  const int wn = (wave & 1) * 32;
  f4v acc[2][2] = {};
  const int ar = tid >> 2, ac = (tid & 3) * 8;
  const int bk = tid >> 3, bn = (tid & 7) * 8;
  for (int k0 = 0; k0 < K; k0 += 32) {
    s8v av;
    if constexpr (AF32) {
      const float* a = (const float*)Ap + (size_t)(m0 + ar) * lda + ac + k0;
      f4v v0 = *reinterpret_cast<const f4v*>(a);
      f4v v1 = *reinterpret_cast<const f4v*>(a + 4);
#pragma unroll
      for (int j = 0; j < 4; ++j) { av[j] = (short)f2bf(v0[j]); av[j + 4] = (short)f2bf(v1[j]); }
    } else {
      av = *reinterpret_cast<const s8v*>((const unsigned short*)Ap + (size_t)(m0 + ar) * lda + ac + k0);
    }
    unsigned short bvs[8];
    if constexpr (BF32) {
      const float* bp = (const float*)Bp + (size_t)(k0 + bk) * N + n0 + bn;
      f4v v0 = *reinterpret_cast<const f4v*>(bp);
      f4v v1 = *reinterpret_cast<const f4v*>(bp + 4);
#pragma unroll
      for (int j = 0; j < 4; ++j) { bvs[j] = f2bf(v0[j]); bvs[j + 4] = f2bf(v1[j]); }
    } else {
      s8v bv = *reinterpret_cast<const s8v*>((const unsigned short*)Bp + (size_t)(k0 + bk) * N + n0 + bn);
#pragma unroll
      for (int j = 0; j < 8; ++j) bvs[j] = (unsigned short)bv[j];
    }
    *reinterpret_cast<s8v*>(&As[ar][ac]) = av;
#pragma unroll
    for (int j = 0; j < 8; ++j) Bs[bn + j][bk] = bvs[j];
    __syncthreads();
#pragma unroll
    for (int mi = 0; mi < 2; ++mi) {
      s8v af = *reinterpret_cast<const s8v*>(&As[wm + mi * 16 + la][quad * 8]);
#pragma unroll
      for (int ni = 0; ni < 2; ++ni) {
        s8v bfr = *reinterpret_cast<const s8v*>(&Bs[wn + ni * 16 + la][quad * 8]);
        acc[mi][ni] = __builtin_amdgcn_mfma_f32_16x16x32_bf16(af, bfr, acc[mi][ni], 0, 0, 0);
      }
    }
    __syncthreads();
  }
#pragma unroll
  for (int mi = 0; mi < 2; ++mi)
#pragma unroll
    for (int ni = 0; ni < 2; ++ni)
#pragma unroll
      for (int r = 0; r < 4; ++r) {
        int row = m0 + wm + mi * 16 + quad * 4 + r;
        int col = n0 + wn + ni * 16 + la;
        if constexpr (CF32) ((float*)Cp)[(size_t)row * N + col] = acc[mi][ni][r];
        else ((unsigned short*)Cp)[(size_t)row * N + col] = f2bf(acc[mi][ni][r]);
      }
}

// ---------------- shared kernels (work for 1 batch or all batches) ----------------

// In-place RMSNorm + RoPE on qkv [nBS, EQKV]; grid (36, nBS). cos/sin fp32, s-indexed.
__global__ __launch_bounds__(64) void norm_rope(unsigned short* __restrict__ qkv,
                                                const float* __restrict__ qw,
                                                const float* __restrict__ kw,
                                                const float* __restrict__ cosp,
                                                const float* __restrict__ sinp) {
  const int h = blockIdx.x;
  const int bs = blockIdx.y;
  const int s = bs & (SS - 1);
  const int lane = threadIdx.x;
  const int d0 = lane * 2;
  unsigned short* p = qkv + (size_t)bs * EQKV + h * DD + d0;
  unsigned int u = *reinterpret_cast<const unsigned int*>(p);
  float x0 = bf2f((unsigned short)(u & 0xffff));
  float x1 = bf2f((unsigned short)(u >> 16));
  float ss = x0 * x0 + x1 * x1;
#pragma unroll
  for (int off = 32; off >= 1; off >>= 1) ss += __shfl_xor(ss, off);
  float rs = rsqrtf(ss * (1.0f / 128.0f) + 1e-6f);
  const float* w = (h < NQH) ? qw : kw;
  float n0 = x0 * rs * w[d0];
  float n1 = x1 * rs * w[d0 + 1];
  float o0 = __shfl_xor(n0, 32);
  float o1 = __shfl_xor(n1, 32);
  float r0 = (lane < 32) ? -o0 : o0;
  float r1 = (lane < 32) ? -o1 : o1;
  float c0 = cosp[(size_t)s * DD + d0], c1 = cosp[(size_t)s * DD + d0 + 1];
  float s0 = sinp[(size_t)s * DD + d0], s1 = sinp[(size_t)s * DD + d0 + 1];
  float y0 = n0 * c0 + r0 * s0;
  float y1 = n1 * c1 + r1 * s1;
  unsigned int outv = (unsigned int)f2bf(y0) | ((unsigned int)f2bf(y1) << 16);
  *reinterpret_cast<unsigned int*>(p) = outv;
}

// Flash attention on qkv [B, SS, EQKV]; grid (64, 32, B); writes O over Q slice.
__global__ __launch_bounds__(64) void attn(unsigned short* __restrict__ qkv) {
  const int tile = blockIdx.x;
  const int h = blockIdx.y;
  const int b = blockIdx.z;
  const int hkv = h >> 3;
  const int lane = threadIdx.x;
  const int la = lane & 15;
  const int quad = lane >> 4;
  const int qr0 = tile * 16;
  __shared__ unsigned short P[16][32];
  __shared__ unsigned short V[32][128];

  const size_t base = (size_t)b * SS * EQKV;
  s8v qf[4];
  {
    const unsigned short* qrow = qkv + base + (size_t)(qr0 + la) * EQKV + h * DD;
#pragma unroll
    for (int t = 0; t < 4; ++t)
      qf[t] = *reinterpret_cast<const s8v*>(qrow + t * 32 + quad * 8);
  }
  const unsigned short* kbase = qkv + base + (NQH + hkv) * DD;
  const unsigned short* vbase = qkv + base + (NQH + NKVH + hkv) * DD;

  float m[4], l[4], al[4];
  f4v acc[8] = {};
#pragma unroll
  for (int r = 0; r < 4; ++r) { m[r] = -1.0e30f; l[r] = 0.f; }

  const float scale = 0.08838834764831845f;
  const int nkb = (qr0 + 16 + 31) >> 5;
  for (int kb = 0; kb < nkb; ++kb) {
    const int key0 = kb * 32;
    __syncthreads();
#pragma unroll
    for (int i = 0; i < 8; ++i) {
      int c = i * 64 + lane;
      int row = c >> 4, col = (c & 15) * 8;
      *reinterpret_cast<s8v*>(&V[row][col]) =
          *reinterpret_cast<const s8v*>(vbase + (size_t)(key0 + row) * EQKV + col);
    }
    f4v s0 = {}, s1 = {};
#pragma unroll
    for (int t = 0; t < 4; ++t) {
      s8v k0f = *reinterpret_cast<const s8v*>(kbase + (size_t)(key0 + la) * EQKV + t * 32 + quad * 8);
      s8v k1f = *reinterpret_cast<const s8v*>(kbase + (size_t)(key0 + 16 + la) * EQKV + t * 32 + quad * 8);
      s0 = __builtin_amdgcn_mfma_f32_16x16x32_bf16(qf[t], k0f, s0, 0, 0, 0);
      s1 = __builtin_amdgcn_mfma_f32_16x16x32_bf16(qf[t], k1f, s1, 0, 0, 0);
    }
#pragma unroll
    for (int r = 0; r < 4; ++r) {
      int q = qr0 + quad * 4 + r;
      float v0 = (key0 + la <= q) ? s0[r] * scale : -1.0e30f;
      float v1 = (key0 + 16 + la <= q) ? s1[r] * scale : -1.0e30f;
      float mx = fmaxf(v0, v1);
#pragma unroll
      for (int off = 8; off >= 1; off >>= 1) mx = fmaxf(mx, __shfl_xor(mx, off));
      float mnew = fmaxf(m[r], mx);
      float p0 = __expf(v0 - mnew);
      float p1 = __expf(v1 - mnew);
      al[r] = __expf(m[r] - mnew);
      m[r] = mnew;
      float rsum = p0 + p1;
#pragma unroll
      for (int off = 8; off >= 1; off >>= 1) rsum += __shfl_xor(rsum, off);
      l[r] = l[r] * al[r] + rsum;
      P[quad * 4 + r][la] = f2bf(p0);
      P[quad * 4 + r][la + 16] = f2bf(p1);
    }
#pragma unroll
    for (int nt = 0; nt < 8; ++nt)
#pragma unroll
      for (int r = 0; r < 4; ++r) acc[nt][r] *= al[r];
    __syncthreads();
    s8v pf = *reinterpret_cast<const s8v*>(&P[la][quad * 8]);
#pragma unroll
    for (int nt = 0; nt < 8; ++nt) {
      s8v vf;
#pragma unroll
      for (int j = 0; j < 8; ++j)
        vf[j] = (short)V[quad * 8 + j][nt * 16 + la];
      acc[nt] = __builtin_amdgcn_mfma_f32_16x16x32_bf16(pf, vf, acc[nt], 0, 0, 0);
    }
  }
#pragma unroll
  for (int nt = 0; nt < 8; ++nt)
#pragma unroll
    for (int r = 0; r < 4; ++r) {
      int q = qr0 + quad * 4 + r;
      qkv[base + (size_t)q * EQKV + h * DD + nt * 16 + la] = f2bf(acc[nt][r] / l[r]);
    }
}

extern "C" void kernel_launch(void* const* d_in, const int* in_sizes, int n_in,
                              void* d_out, int out_size, void* d_ws, size_t ws_size,
                              hipStream_t stream) {
  const float* hidden = (const float*)d_in[0];   // [B,S,H] fp32
  const float* w_qkv  = (const float*)d_in[1];   // [H, 5120] fp32
  const float* w_o    = (const float*)d_in[2];   // [4096, H] fp32
  const float* q_w    = (const float*)d_in[3];
  const float* k_w    = (const float*)d_in[4];
  const float* cosp   = (const float*)d_in[5];
  const float* sinp   = (const float*)d_in[6];
  float* out = (float*)d_out;                    // [B,S,H] fp32

  const int M = BB * SS;  // 4096
  const size_t szHid  = (size_t)M * HH;          // 8.39M elems
  const size_t szWqkv = (size_t)HH * EQKV;       // 10.49M
  const size_t szWo   = (size_t)(NQH * DD) * HH; // 8.39M
  const size_t szQkv  = (size_t)M * EQKV;        // 21.0M
  const size_t need = (szHid + szWqkv + szWo + szQkv) * sizeof(unsigned short); // ~96.5 MB

  if (ws_size >= need) {
    // -------- fast path: pre-converted bf16 + transposed weights, m97 GEMMs --------
    unsigned short* hb16  = (unsigned short*)d_ws;
    unsigned short* wqkvT = hb16 + szHid;    // [5120, 2048]
    unsigned short* woT   = wqkvT + szWqkv;  // [2048, 4096]
    unsigned short* qkv   = woT + szWo;      // [4096, 5120]

    cvt_bf16<<<(int)(szHid / 1024), 256, 0, stream>>>(hidden, hb16, (int)szHid);
    transpose_cvt<<<dim3(EQKV / 64, HH / 64), 256, 0, stream>>>(w_qkv, wqkvT, HH, EQKV);
    transpose_cvt<<<dim3(HH / 64, (NQH * DD) / 64), 256, 0, stream>>>(w_o, woT, NQH * DD, HH);

    // 1) QKV projection: [4096,2048] @ [2048,5120] -> qkv (bf16)
    gemm_bt<false><<<dim3(EQKV / 128, M / 128), 256, 0, stream>>>(
        hb16, wqkvT, qkv, M, EQKV, HH, HH);
    // 2) RMSNorm + RoPE
    norm_rope<<<dim3(NQH + NKVH, M), 64, 0, stream>>>(qkv, q_w, k_w, cosp, sinp);
    // 3) attention (O overwrites Q slice)
    attn<<<dim3(SS / 16, NQH, BB), 64, 0, stream>>>(qkv);
    // 4) out projection: [4096,4096](lda=5120) @ woT^T -> out fp32
    gemm_bt<true><<<dim3(HH / 128, M / 128), 256, 0, stream>>>(
        qkv, woT, out, M, HH, NQH * DD, EQKV);
  } else {
    // -------- fallback: round-3 per-batch path (10 MiB ws) --------
    unsigned short* qkvb = (unsigned short*)d_ws;
    for (int b = 0; b < BB; ++b) {
      const float* hb = hidden + (size_t)b * SS * HH;
      float* ob = out + (size_t)b * SS * HH;
      gemm_t<true, true, false><<<dim3(EQKV / 64, SS / 64), 256, 0, stream>>>(
          hb, w_qkv, qkvb, SS, EQKV, HH, HH);
      norm_rope<<<dim3(NQH + NKVH, SS), 64, 0, stream>>>(qkvb, q_w, k_w, cosp, sinp);
      attn<<<dim3(SS / 16, NQH, 1), 64, 0, stream>>>(qkvb);
      gemm_t<false, true, true><<<dim3(HH / 64, SS / 64), 256, 0, stream>>>(
          qkvb, w_o, ob, SS, HH, NQH * DD, EQKV);
    }
  }
}

// Round 6
// 587.139 us; speedup vs baseline: 2.7214x; 1.2926x over previous
//
#include <hip/hip_runtime.h>

#define BB 4
#define SS 1024
#define HH 2048
#define NQH 32
#define NKVH 4
#define DD 128
#define EQKV 5120   // (NQH + 2*NKVH) * DD

typedef __attribute__((ext_vector_type(8))) short s8v;
typedef __attribute__((ext_vector_type(4))) short s4v;
typedef __attribute__((ext_vector_type(4))) float f4v;

__device__ __forceinline__ unsigned short f2bf(float f) {
  unsigned int u = __builtin_bit_cast(unsigned int, f);
  u += 0x7fffu + ((u >> 16) & 1u);
  return (unsigned short)(u >> 16);
}
__device__ __forceinline__ float bf2f(unsigned short s) {
  unsigned int u = ((unsigned int)s) << 16;
  return __builtin_bit_cast(float, u);
}

// async global->LDS, 16B per lane. LDS dst = wave-uniform base + lane*16 (m104).
__device__ __forceinline__ void async16(unsigned short* lds, const unsigned short* g) {
  __builtin_amdgcn_global_load_lds(
      (const __attribute__((address_space(1))) unsigned int*)g,
      (__attribute__((address_space(3))) unsigned int*)lds, 16, 0, 0);
}

// ---------------- fast path kernels ----------------

// fp32 -> bf16 elementwise, 4 elems/thread. n divisible by 4.
__global__ __launch_bounds__(256) void cvt_bf16(const float* __restrict__ in,
                                                unsigned short* __restrict__ out, int n) {
  int i = (blockIdx.x * 256 + threadIdx.x) * 4;
  if (i >= n) return;
  f4v v = *reinterpret_cast<const f4v*>(in + i);
  s4v o;
#pragma unroll
  for (int j = 0; j < 4; ++j) o[j] = (short)f2bf(v[j]);
  *reinterpret_cast<s4v*>(out + i) = o;
}

// out[n][k] = bf16(in[k][n]); in fp32 [K][N]. 64x64 LDS tile.
__global__ __launch_bounds__(256) void transpose_cvt(const float* __restrict__ in,
                                                     unsigned short* __restrict__ out,
                                                     int K, int N) {
  __shared__ unsigned short T[64][65];
  const int k0 = blockIdx.y * 64, n0 = blockIdx.x * 64;
  const int t = threadIdx.x;
  const int r = t >> 4, c4 = (t & 15) * 4;
#pragma unroll
  for (int i = 0; i < 4; ++i) {
    f4v v = *reinterpret_cast<const f4v*>(&in[(size_t)(k0 + r + i * 16) * N + n0 + c4]);
#pragma unroll
    for (int j = 0; j < 4; ++j) T[r + i * 16][c4 + j] = f2bf(v[j]);
  }
  __syncthreads();
#pragma unroll
  for (int i = 0; i < 4; ++i) {
    int n = r + i * 16;
    s4v o;
#pragma unroll
    for (int j = 0; j < 4; ++j) o[j] = (short)T[c4 + j][n];
    *reinterpret_cast<s4v*>(&out[(size_t)(n0 + n) * K + k0 + c4]) = o;
  }
}

// Vt[(b*NKVH+hkv)*DD + d][s] = qkv[b*SS+s][(NQH+NKVH+hkv)*DD + d]  (bf16 -> bf16)
__global__ __launch_bounds__(256) void vtrans(const unsigned short* __restrict__ qkv,
                                              unsigned short* __restrict__ Vt) {
  __shared__ unsigned short T[64][68];   // [s][d] tile, pad to 68 (136B rows, 8B-aligned)
  const int s0 = blockIdx.x * 64;
  const int d0 = blockIdx.y * 64;       // 0 or 64
  const int bk = blockIdx.z;            // b*NKVH + hkv
  const int b = bk >> 2, hkv = bk & 3;
  const int t = threadIdx.x;
  const int r = t >> 4, c4 = (t & 15) * 4;
  const unsigned short* src = qkv + (size_t)(b * SS + s0) * EQKV + (NQH + NKVH + hkv) * DD + d0;
#pragma unroll
  for (int i = 0; i < 4; ++i) {
    int s = r + i * 16;
    s4v v = *reinterpret_cast<const s4v*>(src + (size_t)s * EQKV + c4);
    *reinterpret_cast<s4v*>(&T[s][c4]) = v;
  }
  __syncthreads();
#pragma unroll
  for (int i = 0; i < 4; ++i) {
    int d = r + i * 16;
    s4v o;
#pragma unroll
    for (int j = 0; j < 4; ++j) o[j] = (short)T[c4 + j][d];
    *reinterpret_cast<s4v*>(&Vt[((size_t)bk * DD + d0 + d) * SS + s0 + c4]) = o;
  }
}

// m97-structure GEMM: C[M,N] = A[M,K](lda) @ Bt[N,K]^T, bf16 in, fp32 acc.
template <bool CF32>
__global__ __launch_bounds__(256) void gemm_bt(const unsigned short* __restrict__ A,
                                               const unsigned short* __restrict__ Bt,
                                               void* __restrict__ Cp,
                                               int M, int N, int K, int lda) {
  __shared__ unsigned short As[128 * 32];
  __shared__ unsigned short Bs[128 * 32];
  const int tid = threadIdx.x;
  const int ln = tid & 63, wv = tid >> 6;
  const int la = ln & 15, quad = ln >> 4;
  const int m0 = blockIdx.y * 128, n0 = blockIdx.x * 128;
  const int wm = (wv >> 1) * 64, wn = (wv & 1) * 64;
  f4v acc[4][4] = {};

  const int srow = wv * 16 + (ln >> 2);
  const int scol = (ln & 3) * 8;
  const unsigned short* Ab = A + (size_t)(m0 + srow) * lda + scol;
  const unsigned short* Bb = Bt + (size_t)(n0 + srow) * K + scol;
  unsigned short* AsW = &As[wv * 16 * 32];
  unsigned short* BsW = &Bs[wv * 16 * 32];

  for (int k0 = 0; k0 < K; k0 += 32) {
    async16(AsW,           Ab + k0);
    async16(AsW + 64 * 32, Ab + (size_t)64 * lda + k0);
    async16(BsW,           Bb + k0);
    async16(BsW + 64 * 32, Bb + (size_t)64 * K + k0);
    __syncthreads();
    s8v af[4], bf[4];
#pragma unroll
    for (int mi = 0; mi < 4; ++mi)
      af[mi] = *reinterpret_cast<const s8v*>(&As[(wm + mi * 16 + la) * 32 + quad * 8]);
#pragma unroll
    for (int ni = 0; ni < 4; ++ni)
      bf[ni] = *reinterpret_cast<const s8v*>(&Bs[(wn + ni * 16 + la) * 32 + quad * 8]);
#pragma unroll
    for (int mi = 0; mi < 4; ++mi)
#pragma unroll
      for (int ni = 0; ni < 4; ++ni)
        acc[mi][ni] = __builtin_amdgcn_mfma_f32_16x16x32_bf16(af[mi], bf[ni], acc[mi][ni], 0, 0, 0);
    __syncthreads();
  }
#pragma unroll
  for (int mi = 0; mi < 4; ++mi)
#pragma unroll
    for (int ni = 0; ni < 4; ++ni)
#pragma unroll
      for (int r = 0; r < 4; ++r) {
        int row = m0 + wm + mi * 16 + quad * 4 + r;
        int col = n0 + wn + ni * 16 + la;
        if constexpr (CF32) ((float*)Cp)[(size_t)row * N + col] = acc[mi][ni][r];
        else ((unsigned short*)Cp)[(size_t)row * N + col] = f2bf(acc[mi][ni][r]);
      }
}

// ---------------- new attention ----------------
// Block = 256 thr (4 waves), Q-tile 64 rows of one head, key-blocks of 64.
// K[64][128] + Vt[128][64] staged via global_load_lds with XOR chunk swizzle;
// wave w owns q-rows qr0+w*16..+15. O overwrites the Q slice of qkv.
__global__ __launch_bounds__(256) void attn2(unsigned short* __restrict__ qkv,
                                             const unsigned short* __restrict__ Vt) {
  const int tile = blockIdx.x;   // 0..15
  const int h = blockIdx.y;      // 0..31
  const int b = blockIdx.z;      // 0..3
  const int hkv = h >> 3;
  const int tid = threadIdx.x;
  const int ln = tid & 63, w = tid >> 6;
  const int la = ln & 15, quad = ln >> 4;
  const int qr0 = tile * 64;
  __shared__ unsigned short Ks[64 * 128];    // [key][d], chunk-swizzled ^ (key&15)
  __shared__ unsigned short Vts[128 * 64];   // [d][key], chunk-swizzled ^ (d&7)
  __shared__ unsigned short Ps[4][16][72];   // per-wave P[16 q][64 key], pad 8

  const size_t rowb = (size_t)b * SS;
  s8v qf[4];
  {
    const unsigned short* qrow = qkv + (rowb + qr0 + w * 16 + la) * EQKV + h * DD;
#pragma unroll
    for (int t = 0; t < 4; ++t) qf[t] = *reinterpret_cast<const s8v*>(qrow + t * 32 + quad * 8);
  }
  const unsigned short* kcol = qkv + (NQH + hkv) * DD;
  const unsigned short* vtb = Vt + (size_t)(b * NKVH + hkv) * DD * SS;

  float m_[4], l_[4], al[4];
  f4v acc[8] = {};
#pragma unroll
  for (int r = 0; r < 4; ++r) { m_[r] = -1.0e30f; l_[r] = 0.f; }

  const float scale = 0.08838834764831845f;  // 1/sqrt(128)
  const int nkb = qr0 / 64 + 1;
  for (int kb = 0; kb < nkb; ++kb) {
    const int key0 = kb * 64;
    __syncthreads();  // prev-iter LDS reads complete
    // stage K rows w*16..w*16+15 (4 calls x 4 rows), swizzle chunk ^= row&15
#pragma unroll
    for (int i = 0; i < 4; ++i) {
      int row = w * 16 + i * 4 + (ln >> 4);
      int chunk = (ln & 15) ^ (row & 15);
      async16(&Ks[(w * 16 + i * 4) * 128],
              kcol + (rowb + key0 + row) * EQKV + chunk * 8);
    }
    // stage Vt rows d = w*32..w*32+31 (4 calls x 8 rows), swizzle chunk ^= d&7
#pragma unroll
    for (int i = 0; i < 4; ++i) {
      int row = w * 32 + i * 8 + (ln >> 3);
      int chunk = (ln & 7) ^ (ln >> 3);
      async16(&Vts[(w * 32 + i * 8) * 64],
              vtb + (size_t)row * SS + key0 + chunk * 8);
    }
    __syncthreads();  // staging visible
    // QK^T: 4 key-tiles x 4 d-chunks
    f4v sc[4];
#pragma unroll
    for (int kt = 0; kt < 4; ++kt) {
      f4v z = {};
#pragma unroll
      for (int t = 0; t < 4; ++t) {
        s8v kf = *reinterpret_cast<const s8v*>(&Ks[(kt * 16 + la) * 128 + ((t * 4 + quad) ^ la) * 8]);
        z = __builtin_amdgcn_mfma_f32_16x16x32_bf16(qf[t], kf, z, 0, 0, 0);
      }
      sc[kt] = z;
    }
    // online softmax over 64 keys; row = w*16 + quad*4 + r
#pragma unroll
    for (int r = 0; r < 4; ++r) {
      int q = qr0 + w * 16 + quad * 4 + r;
      float v[4];
#pragma unroll
      for (int kt = 0; kt < 4; ++kt)
        v[kt] = (key0 + kt * 16 + la <= q) ? sc[kt][r] * scale : -1.0e30f;
      float mx = fmaxf(fmaxf(v[0], v[1]), fmaxf(v[2], v[3]));
#pragma unroll
      for (int off = 8; off >= 1; off >>= 1) mx = fmaxf(mx, __shfl_xor(mx, off));
      float mnew = fmaxf(m_[r], mx);
      al[r] = __expf(m_[r] - mnew);
      m_[r] = mnew;
      float rsum = 0.f;
#pragma unroll
      for (int kt = 0; kt < 4; ++kt) {
        float p = __expf(v[kt] - mnew);
        rsum += p;
        Ps[w][quad * 4 + r][kt * 16 + la] = f2bf(p);
      }
#pragma unroll
      for (int off = 8; off >= 1; off >>= 1) rsum += __shfl_xor(rsum, off);
      l_[r] = l_[r] * al[r] + rsum;
    }
#pragma unroll
    for (int nt = 0; nt < 8; ++nt)
#pragma unroll
      for (int r = 0; r < 4; ++r) acc[nt][r] *= al[r];
    // PV (Ps same-wave: DS in-order; Vts covered by staging barrier)
#pragma unroll
    for (int c = 0; c < 2; ++c) {
      s8v pf = *reinterpret_cast<const s8v*>(&Ps[w][la][c * 32 + quad * 8]);
#pragma unroll
      for (int nt = 0; nt < 8; ++nt) {
        s8v vf = *reinterpret_cast<const s8v*>(
            &Vts[(nt * 16 + la) * 64 + ((c * 4 + quad) ^ (la & 7)) * 8]);
        acc[nt] = __builtin_amdgcn_mfma_f32_16x16x32_bf16(pf, vf, acc[nt], 0, 0, 0);
      }
    }
  }
#pragma unroll
  for (int nt = 0; nt < 8; ++nt)
#pragma unroll
    for (int r = 0; r < 4; ++r) {
      int q = qr0 + w * 16 + quad * 4 + r;
      qkv[(rowb + q) * EQKV + h * DD + nt * 16 + la] = f2bf(acc[nt][r] / l_[r]);
    }
}

// ---------------- slow-path (fallback) kernels ----------------
template <bool AF32, bool BF32, bool CF32>
__global__ __launch_bounds__(256) void gemm_t(const void* __restrict__ Ap,
                                              const void* __restrict__ Bp,
                                              void* __restrict__ Cp,
                                              int M, int N, int K, int lda) {
  __shared__ unsigned short As[64][40];
  __shared__ unsigned short Bs[64][40];
  const int tid  = threadIdx.x;
  const int lane = tid & 63;
  const int wave = tid >> 6;
  const int la   = lane & 15;
  const int quad = lane >> 4;
  const int m0 = blockIdx.y * 64;
  const int n0 = blockIdx.x * 64;
  const int wm = (wave >> 1) * 32;
  const int wn = (wave & 1) * 32;
  f4v acc[2][2] = {};
  const int ar = tid >> 2, ac = (tid & 3) * 8;
  const int bk = tid >> 3, bn = (tid & 7) * 8;
  for (int k0 = 0; k0 < K; k0 += 32) {
    s8v av;
    if constexpr (AF32) {
      const float* a = (const float*)Ap + (size_t)(m0 + ar) * lda + ac + k0;
      f4v v0 = *reinterpret_cast<const f4v*>(a);
      f4v v1 = *reinterpret_cast<const f4v*>(a + 4);
#pragma unroll
      for (int j = 0; j < 4; ++j) { av[j] = (short)f2bf(v0[j]); av[j + 4] = (short)f2bf(v1[j]); }
    } else {
      av = *reinterpret_cast<const s8v*>((const unsigned short*)Ap + (size_t)(m0 + ar) * lda + ac + k0);
    }
    unsigned short bvs[8];
    if constexpr (BF32) {
      const float* bp = (const float*)Bp + (size_t)(k0 + bk) * N + n0 + bn;
      f4v v0 = *reinterpret_cast<const f4v*>(bp);
      f4v v1 = *reinterpret_cast<const f4v*>(bp + 4);
#pragma unroll
      for (int j = 0; j < 4; ++j) { bvs[j] = f2bf(v0[j]); bvs[j + 4] = f2bf(v1[j]); }
    } else {
      s8v bv = *reinterpret_cast<const s8v*>((const unsigned short*)Bp + (size_t)(k0 + bk) * N + n0 + bn);
#pragma unroll
      for (int j = 0; j < 8; ++j) bvs[j] = (unsigned short)bv[j];
    }
    *reinterpret_cast<s8v*>(&As[ar][ac]) = av;
#pragma unroll
    for (int j = 0; j < 8; ++j) Bs[bn + j][bk] = bvs[j];
    __syncthreads();
#pragma unroll
    for (int mi = 0; mi < 2; ++mi) {
      s8v af = *reinterpret_cast<const s8v*>(&As[wm + mi * 16 + la][quad * 8]);
#pragma unroll
      for (int ni = 0; ni < 2; ++ni) {
        s8v bfr = *reinterpret_cast<const s8v*>(&Bs[wn + ni * 16 + la][quad * 8]);
        acc[mi][ni] = __builtin_amdgcn_mfma_f32_16x16x32_bf16(af, bfr, acc[mi][ni], 0, 0, 0);
      }
    }
    __syncthreads();
  }
#pragma unroll
  for (int mi = 0; mi < 2; ++mi)
#pragma unroll
    for (int ni = 0; ni < 2; ++ni)
#pragma unroll
      for (int r = 0; r < 4; ++r) {
        int row = m0 + wm + mi * 16 + quad * 4 + r;
        int col = n0 + wn + ni * 16 + la;
        if constexpr (CF32) ((float*)Cp)[(size_t)row * N + col] = acc[mi][ni][r];
        else ((unsigned short*)Cp)[(size_t)row * N + col] = f2bf(acc[mi][ni][r]);
      }
}

__global__ __launch_bounds__(64) void attn_slow(unsigned short* __restrict__ qkv) {
  const int tile = blockIdx.x;
  const int h = blockIdx.y;
  const int b = blockIdx.z;
  const int hkv = h >> 3;
  const int lane = threadIdx.x;
  const int la = lane & 15;
  const int quad = lane >> 4;
  const int qr0 = tile * 16;
  __shared__ unsigned short P[16][32];
  __shared__ unsigned short V[32][128];
  const size_t base = (size_t)b * SS * EQKV;
  s8v qf[4];
  {
    const unsigned short* qrow = qkv + base + (size_t)(qr0 + la) * EQKV + h * DD;
#pragma unroll
    for (int t = 0; t < 4; ++t)
      qf[t] = *reinterpret_cast<const s8v*>(qrow + t * 32 + quad * 8);
  }
  const unsigned short* kbase = qkv + base + (NQH + hkv) * DD;
  const unsigned short* vbase = qkv + base + (NQH + NKVH + hkv) * DD;
  float m[4], l[4], al[4];
  f4v acc[8] = {};
#pragma unroll
  for (int r = 0; r < 4; ++r) { m[r] = -1.0e30f; l[r] = 0.f; }
  const float scale = 0.08838834764831845f;
  const int nkb = (qr0 + 16 + 31) >> 5;
  for (int kb = 0; kb < nkb; ++kb) {
    const int key0 = kb * 32;
    __syncthreads();
#pragma unroll
    for (int i = 0; i < 8; ++i) {
      int c = i * 64 + lane;
      int row = c >> 4, col = (c & 15) * 8;
      *reinterpret_cast<s8v*>(&V[row][col]) =
          *reinterpret_cast<const s8v*>(vbase + (size_t)(key0 + row) * EQKV + col);
    }
    f4v s0 = {}, s1 = {};
#pragma unroll
    for (int t = 0; t < 4; ++t) {
      s8v k0f = *reinterpret_cast<const s8v*>(kbase + (size_t)(key0 + la) * EQKV + t * 32 + quad * 8);
      s8v k1f = *reinterpret_cast<const s8v*>(kbase + (size_t)(key0 + 16 + la) * EQKV + t * 32 + quad * 8);
      s0 = __builtin_amdgcn_mfma_f32_16x16x32_bf16(qf[t], k0f, s0, 0, 0, 0);
      s1 = __builtin_amdgcn_mfma_f32_16x16x32_bf16(qf[t], k1f, s1, 0, 0, 0);
    }
#pragma unroll
    for (int r = 0; r < 4; ++r) {
      int q = qr0 + quad * 4 + r;
      float v0 = (key0 + la <= q) ? s0[r] * scale : -1.0e30f;
      float v1 = (key0 + 16 + la <= q) ? s1[r] * scale : -1.0e30f;
      float mx = fmaxf(v0, v1);
#pragma unroll
      for (int off = 8; off >= 1; off >>= 1) mx = fmaxf(mx, __shfl_xor(mx, off));
      float mnew = fmaxf(m[r], mx);
      float p0 = __expf(v0 - mnew);
      float p1 = __expf(v1 - mnew);
      al[r] = __expf(m[r] - mnew);
      m[r] = mnew;
      float rsum = p0 + p1;
#pragma unroll
      for (int off = 8; off >= 1; off >>= 1) rsum += __shfl_xor(rsum, off);
      l[r] = l[r] * al[r] + rsum;
      P[quad * 4 + r][la] = f2bf(p0);
      P[quad * 4 + r][la + 16] = f2bf(p1);
    }
#pragma unroll
    for (int nt = 0; nt < 8; ++nt)
#pragma unroll
      for (int r = 0; r < 4; ++r) acc[nt][r] *= al[r];
    __syncthreads();
    s8v pf = *reinterpret_cast<const s8v*>(&P[la][quad * 8]);
#pragma unroll
    for (int nt = 0; nt < 8; ++nt) {
      s8v vf;
#pragma unroll
      for (int j = 0; j < 8; ++j)
        vf[j] = (short)V[quad * 8 + j][nt * 16 + la];
      acc[nt] = __builtin_amdgcn_mfma_f32_16x16x32_bf16(pf, vf, acc[nt], 0, 0, 0);
    }
  }
#pragma unroll
  for (int nt = 0; nt < 8; ++nt)
#pragma unroll
    for (int r = 0; r < 4; ++r) {
      int q = qr0 + quad * 4 + r;
      qkv[base + (size_t)q * EQKV + h * DD + nt * 16 + la] = f2bf(acc[nt][r] / l[r]);
    }
}

// In-place RMSNorm + RoPE (shared by both paths)
__global__ __launch_bounds__(64) void norm_rope(unsigned short* __restrict__ qkv,
                                                const float* __restrict__ qw,
                                                const float* __restrict__ kw,
                                                const float* __restrict__ cosp,
                                                const float* __restrict__ sinp) {
  const int h = blockIdx.x;
  const int bs = blockIdx.y;
  const int s = bs & (SS - 1);
  const int lane = threadIdx.x;
  const int d0 = lane * 2;
  unsigned short* p = qkv + (size_t)bs * EQKV + h * DD + d0;
  unsigned int u = *reinterpret_cast<const unsigned int*>(p);
  float x0 = bf2f((unsigned short)(u & 0xffff));
  float x1 = bf2f((unsigned short)(u >> 16));
  float ss = x0 * x0 + x1 * x1;
#pragma unroll
  for (int off = 32; off >= 1; off >>= 1) ss += __shfl_xor(ss, off);
  float rs = rsqrtf(ss * (1.0f / 128.0f) + 1e-6f);
  const float* w = (h < NQH) ? qw : kw;
  float n0 = x0 * rs * w[d0];
  float n1 = x1 * rs * w[d0 + 1];
  float o0 = __shfl_xor(n0, 32);
  float o1 = __shfl_xor(n1, 32);
  float r0 = (lane < 32) ? -o0 : o0;
  float r1 = (lane < 32) ? -o1 : o1;
  float c0 = cosp[(size_t)s * DD + d0], c1 = cosp[(size_t)s * DD + d0 + 1];
  float s0 = sinp[(size_t)s * DD + d0], s1 = sinp[(size_t)s * DD + d0 + 1];
  float y0 = n0 * c0 + r0 * s0;
  float y1 = n1 * c1 + r1 * s1;
  unsigned int outv = (unsigned int)f2bf(y0) | ((unsigned int)f2bf(y1) << 16);
  *reinterpret_cast<unsigned int*>(p) = outv;
}

extern "C" void kernel_launch(void* const* d_in, const int* in_sizes, int n_in,
                              void* d_out, int out_size, void* d_ws, size_t ws_size,
                              hipStream_t stream) {
  const float* hidden = (const float*)d_in[0];
  const float* w_qkv  = (const float*)d_in[1];
  const float* w_o    = (const float*)d_in[2];
  const float* q_w    = (const float*)d_in[3];
  const float* k_w    = (const float*)d_in[4];
  const float* cosp   = (const float*)d_in[5];
  const float* sinp   = (const float*)d_in[6];
  float* out = (float*)d_out;

  const int M = BB * SS;  // 4096
  const size_t szHid  = (size_t)M * HH;
  const size_t szWqkv = (size_t)HH * EQKV;
  const size_t szWo   = (size_t)(NQH * DD) * HH;
  const size_t szQkv  = (size_t)M * EQKV;
  const size_t need = (szHid + szWqkv + szWo + szQkv) * sizeof(unsigned short); // ~96.5 MB

  if (ws_size >= need) {
    unsigned short* hb16  = (unsigned short*)d_ws;   // dead after GEMM1; reused for Vt
    unsigned short* wqkvT = hb16 + szHid;
    unsigned short* woT   = wqkvT + szWqkv;
    unsigned short* qkv   = woT + szWo;
    unsigned short* Vt    = hb16;                    // [B*NKVH*DD, SS] = 4.2 MB < 16.8 MB

    cvt_bf16<<<(int)(szHid / 1024), 256, 0, stream>>>(hidden, hb16, (int)szHid);
    transpose_cvt<<<dim3(EQKV / 64, HH / 64), 256, 0, stream>>>(w_qkv, wqkvT, HH, EQKV);
    transpose_cvt<<<dim3(HH / 64, (NQH * DD) / 64), 256, 0, stream>>>(w_o, woT, NQH * DD, HH);

    gemm_bt<false><<<dim3(EQKV / 128, M / 128), 256, 0, stream>>>(
        hb16, wqkvT, qkv, M, EQKV, HH, HH);
    // hb16 now dead -> Vt aliases it
    vtrans<<<dim3(SS / 64, DD / 64, BB * NKVH), 256, 0, stream>>>(qkv, Vt);
    norm_rope<<<dim3(NQH + NKVH, M), 64, 0, stream>>>(qkv, q_w, k_w, cosp, sinp);
    attn2<<<dim3(SS / 64, NQH, BB), 256, 0, stream>>>(qkv, Vt);
    gemm_bt<true><<<dim3(HH / 128, M / 128), 256, 0, stream>>>(
        qkv, woT, out, M, HH, NQH * DD, EQKV);
  } else {
    unsigned short* qkvb = (unsigned short*)d_ws;
    for (int b = 0; b < BB; ++b) {
      const float* hb = hidden + (size_t)b * SS * HH;
      float* ob = out + (size_t)b * SS * HH;
      gemm_t<true, true, false><<<dim3(EQKV / 64, SS / 64), 256, 0, stream>>>(
          hb, w_qkv, qkvb, SS, EQKV, HH, HH);
      norm_rope<<<dim3(NQH + NKVH, SS), 64, 0, stream>>>(qkvb, q_w, k_w, cosp, sinp);
      attn_slow<<<dim3(SS / 16, NQH, 1), 64, 0, stream>>>(qkvb);
      gemm_t<false, true, true><<<dim3(HH / 64, SS / 64), 256, 0, stream>>>(
          qkvb, w_o, ob, SS, HH, NQH * DD, EQKV);
    }
  }
}